// Round 1
// baseline (270.941 us; speedup 1.0000x reference)
//
#include <hip/hip_runtime.h>
#include <math.h>

// Problem constants (from setup_inputs): BS=8, FPS=64, PPF=1024, XC=64, K=64, YS=128
// N = 524288 points, T = N/1024 = 512 tiles (== frames), batch = frame/64.
// CDF = 0.9

// ---------------------------------------------------------------- K1: y_k = y @ Wy.T  (8 x 64)
__global__ __launch_bounds__(512) void yk_kernel(const float* __restrict__ y,
                                                 const float* __restrict__ Wy,
                                                 float* __restrict__ yk) {
    const int tid = threadIdx.x;          // 512 = 8 batches * 64 k
    const int b = tid >> 6, k = tid & 63;
    const float* yrow = y + b * 128;
    const float* wrow = Wy + k * 128;
    float a0 = 0.f, a1 = 0.f, a2 = 0.f, a3 = 0.f;
#pragma unroll
    for (int j = 0; j < 128; j += 4) {
        a0 += yrow[j + 0] * wrow[j + 0];
        a1 += yrow[j + 1] * wrow[j + 1];
        a2 += yrow[j + 2] * wrow[j + 2];
        a3 += yrow[j + 3] * wrow[j + 3];
    }
    yk[tid] = (a0 + a1) + (a2 + a3);
}

// ---------------------------------------------------------------- K2: scores[i] = Wa . tanh(Wc x_i + bc + yk[b]) + ba
__global__ __launch_bounds__(256) void score_kernel(const float* __restrict__ x,
                                                    const float* __restrict__ Wc,
                                                    const float* __restrict__ bc,
                                                    const float* __restrict__ Wa,
                                                    const float* __restrict__ ba,
                                                    const float* __restrict__ yk,
                                                    float* __restrict__ scores) {
    __shared__ float sWc[64 * 64];
    __shared__ float sPre[64];   // bc[k] + yk[b][k]
    __shared__ float sWa[64];
    const int tid = threadIdx.x;
    const int b = blockIdx.x >> 8;                    // 65536 points per batch / 256 per block
    const long long i = (long long)blockIdx.x * 256 + tid;

    for (int j = tid; j < 4096; j += 256) sWc[j] = Wc[j];
    if (tid < 64) {
        sPre[tid] = bc[tid] + yk[b * 64 + tid];
        sWa[tid]  = Wa[tid];
    }
    __syncthreads();

    // x row into registers (16 x float4)
    float xr[64];
    const float4* xp = (const float4*)(x + i * 64);
#pragma unroll
    for (int j = 0; j < 16; ++j) {
        float4 v = xp[j];
        xr[4 * j + 0] = v.x; xr[4 * j + 1] = v.y;
        xr[4 * j + 2] = v.z; xr[4 * j + 3] = v.w;
    }

    float s = 0.f;
#pragma unroll 2
    for (int k = 0; k < 64; ++k) {
        const float* wr = &sWc[k * 64];            // broadcast reads (uniform addr)
        float a0 = 0.f, a1 = 0.f, a2 = 0.f, a3 = 0.f;
#pragma unroll
        for (int c = 0; c < 64; c += 4) {
            a0 += xr[c + 0] * wr[c + 0];
            a1 += xr[c + 1] * wr[c + 1];
            a2 += xr[c + 2] * wr[c + 2];
            a3 += xr[c + 3] * wr[c + 3];
        }
        float v = ((a0 + a1) + (a2 + a3)) + sPre[k];
        s += sWa[k] * tanhf(v);
    }
    scores[i] = s + ba[0];
}

// ---------------------------------------------------------------- K3: per-tile softmax + stable-desc sort + cumsum + keep flags
__global__ __launch_bounds__(1024) void tile_kernel(const float* __restrict__ scores,
                                                    int* __restrict__ flags,
                                                    int* __restrict__ keepcnt) {
    const int t = blockIdx.x, tid = threadIdx.x;
    __shared__ float w[1024];
    __shared__ int   idx[1024];
    __shared__ float red[16];
    __shared__ int   keep_s;

    const int lane = tid & 63, wid = tid >> 6;
    float s = scores[t * 1024 + tid];

    // max reduce
    float m = s;
#pragma unroll
    for (int o = 32; o; o >>= 1) m = fmaxf(m, __shfl_xor(m, o));
    if (lane == 0) red[wid] = m;
    __syncthreads();
    float mb = red[0];
#pragma unroll
    for (int q = 1; q < 16; ++q) mb = fmaxf(mb, red[q]);
    __syncthreads();    // red reused below

    float e = expf(s - mb);
    float su = e;
#pragma unroll
    for (int o = 32; o; o >>= 1) su += __shfl_xor(su, o);
    if (lane == 0) red[wid] = su;
    __syncthreads();
    float tot = 0.f;
#pragma unroll
    for (int q = 0; q < 16; ++q) tot += red[q];

    float wv = e / tot;
    w[tid] = wv;
    idx[tid] = tid;
    __syncthreads();

    // bitonic sort, descending by (w desc, idx asc) — composite key makes order
    // strict & identical to jnp's stable argsort(-w)
    for (int kk = 2; kk <= 1024; kk <<= 1) {
        for (int j = kk >> 1; j > 0; j >>= 1) {
            int p = tid ^ j;
            if (p > tid) {
                float wa = w[tid], wb = w[p];
                int   ia = idx[tid], ib = idx[p];
                bool before = (wa > wb) || (wa == wb && ia < ib);
                bool desc = ((tid & kk) == 0);
                if (desc ? !before : before) {
                    w[tid] = wb; w[p] = wa;
                    idx[tid] = ib; idx[p] = ia;
                }
            }
            __syncthreads();
        }
    }

    // sequential cumsum (matches numpy accumulation order), keep = #(csum<0.9)+1
    if (tid == 0) {
        float c = 0.f; int kp = 0;
        for (int q = 0; q < 1024; ++q) { c += w[q]; if (c < 0.9f) ++kp; }
        keep_s = kp + 1;
        keepcnt[t] = kp + 1;
    }
    __syncthreads();

    // point idx[tid] (sorted position tid) kept iff tid < keep
    flags[t * 1024 + idx[tid]] = (tid < keep_s) ? 1 : 0;
}

// ---------------------------------------------------------------- K4: exclusive scan of per-tile keep counts
__global__ void offsets_kernel(const int* __restrict__ keepcnt, int* __restrict__ toffs, int T) {
    if (threadIdx.x == 0 && blockIdx.x == 0) {
        int r = 0;
        for (int t = 0; t < T; ++t) { toffs[t] = r; r += keepcnt[t]; }
    }
}

// ---------------------------------------------------------------- K5: stream compaction (x rows + locations as float)
__global__ __launch_bounds__(1024) void compact_kernel(const float* __restrict__ x,
                                                       const int* __restrict__ locs,
                                                       const int* __restrict__ flags,
                                                       const int* __restrict__ toffs,
                                                       float* __restrict__ out,
                                                       int M) {
    const int t = blockIdx.x, tid = threadIdx.x;
    const long long gi = (long long)t * 1024 + tid;
    const int f = flags[gi];
    const int lane = tid & 63, wid = tid >> 6;

    unsigned long long ball = __ballot(f != 0);
    int wpre = __popcll(ball & (((unsigned long long)1 << lane) - 1ULL));

    __shared__ int wtot[16];
    __shared__ int woff[16];
    if (lane == 63) wtot[wid] = wpre + f;
    __syncthreads();
    if (tid == 0) {
        int r = 0;
#pragma unroll
        for (int q = 0; q < 16; ++q) { woff[q] = r; r += wtot[q]; }
    }
    __syncthreads();

    if (f) {
        const long long pos = (long long)toffs[t] + woff[wid] + wpre;
        const float4* src = (const float4*)(x + gi * 64);
        float4* dst = (float4*)(out + pos * 64);
#pragma unroll
        for (int j = 0; j < 16; ++j) dst[j] = src[j];
        float* lout = out + (long long)M * 64 + pos * 3;
        lout[0] = (float)locs[gi * 3 + 0];
        lout[1] = (float)locs[gi * 3 + 1];
        lout[2] = (float)locs[gi * 3 + 2];
    }
}

// ----------------------------------------------------------------
extern "C" void kernel_launch(void* const* d_in, const int* in_sizes, int n_in,
                              void* d_out, int out_size, void* d_ws, size_t ws_size,
                              hipStream_t stream) {
    const float* x    = (const float*)d_in[0];
    const int*   locs = (const int*)d_in[1];
    const float* y    = (const float*)d_in[2];
    const float* Wc   = (const float*)d_in[3];
    const float* bc   = (const float*)d_in[4];
    const float* Wy   = (const float*)d_in[5];
    const float* Wa   = (const float*)d_in[6];
    const float* ba   = (const float*)d_in[7];

    const int N = in_sizes[0] / 64;       // 524288
    const int T = N / 1024;               // 512
    const int M = out_size / 67;          // kept points (64 x-cols + 3 loc-cols)

    float* ws      = (float*)d_ws;
    float* yk      = ws;                      // 512 floats
    float* scores  = ws + 512;                // N floats
    int*   flags   = (int*)(ws + 512 + N);    // N ints
    int*   keepcnt = flags + N;               // T ints
    int*   toffs   = keepcnt + T;             // T ints

    yk_kernel<<<1, 512, 0, stream>>>(y, Wy, yk);
    score_kernel<<<N / 256, 256, 0, stream>>>(x, Wc, bc, Wa, ba, yk, scores);
    tile_kernel<<<T, 1024, 0, stream>>>(scores, flags, keepcnt);
    offsets_kernel<<<1, 64, 0, stream>>>(keepcnt, toffs, T);
    compact_kernel<<<T, 1024, 0, stream>>>(x, locs, flags, toffs, (float*)d_out, M);
}

// Round 2
// 236.618 us; speedup vs baseline: 1.1451x; 1.1451x over previous
//
#include <hip/hip_runtime.h>
#include <math.h>

// Problem constants: BS=8, FPS=64, PPF=1024, XC=64, K=64, YS=128
// N = 524288 points, T = 512 tiles (frames), batch = frame/64. CDF = 0.9

// ---------------------------------------------------------------- K1: y_k = y @ Wy.T  (8 x 64)
__global__ __launch_bounds__(512) void yk_kernel(const float* __restrict__ y,
                                                 const float* __restrict__ Wy,
                                                 float* __restrict__ yk) {
    const int tid = threadIdx.x;          // 512 = 8 batches * 64 k
    const int b = tid >> 6, k = tid & 63;
    const float* yrow = y + b * 128;
    const float* wrow = Wy + k * 128;
    float a0 = 0.f, a1 = 0.f, a2 = 0.f, a3 = 0.f;
#pragma unroll
    for (int j = 0; j < 128; j += 4) {
        a0 += yrow[j + 0] * wrow[j + 0];
        a1 += yrow[j + 1] * wrow[j + 1];
        a2 += yrow[j + 2] * wrow[j + 2];
        a3 += yrow[j + 3] * wrow[j + 3];
    }
    yk[tid] = (a0 + a1) + (a2 + a3);
}

// ---------------------------------------------------------------- K2: scores[i] = Wa . tanh(Wc x_i + bc + yk[b]) + ba
// __launch_bounds__(256, 4): 4 waves/EU -> 128 VGPR budget so xr[64] stays
// in registers (round-1 allocation was 48 VGPRs => x re-loaded inside the
// 64x64 FMA loop; that was the 5.6x-over-FMA-floor cost).
__global__ __launch_bounds__(256, 4) void score_kernel(const float* __restrict__ x,
                                                       const float* __restrict__ Wc,
                                                       const float* __restrict__ bc,
                                                       const float* __restrict__ Wa,
                                                       const float* __restrict__ ba,
                                                       const float* __restrict__ yk,
                                                       float* __restrict__ scores) {
    __shared__ float sWc[64 * 64];
    __shared__ float sPre[64];   // bc[k] + yk[b][k]
    __shared__ float sWa[64];
    const int tid = threadIdx.x;
    const int b = blockIdx.x >> 8;                    // 256 blocks per batch
    const long long i = (long long)blockIdx.x * 256 + tid;

    for (int j = tid; j < 4096; j += 256) sWc[j] = Wc[j];
    if (tid < 64) {
        sPre[tid] = bc[tid] + yk[b * 64 + tid];
        sWa[tid]  = Wa[tid];
    }
    __syncthreads();

    // x row into registers (16 x float4)
    float xr[64];
    const float4* xp = (const float4*)(x + i * 64);
#pragma unroll
    for (int j = 0; j < 16; ++j) {
        float4 v = xp[j];
        xr[4 * j + 0] = v.x; xr[4 * j + 1] = v.y;
        xr[4 * j + 2] = v.z; xr[4 * j + 3] = v.w;
    }

    float s = 0.f;
#pragma unroll 2
    for (int k = 0; k < 64; ++k) {
        const float* wr = &sWc[k * 64];            // wave-uniform LDS broadcast
        float a0 = 0.f, a1 = 0.f, a2 = 0.f, a3 = 0.f;
#pragma unroll
        for (int c = 0; c < 64; c += 4) {
            a0 += xr[c + 0] * wr[c + 0];
            a1 += xr[c + 1] * wr[c + 1];
            a2 += xr[c + 2] * wr[c + 2];
            a3 += xr[c + 3] * wr[c + 3];
        }
        float v = ((a0 + a1) + (a2 + a3)) + sPre[k];
        s += sWa[k] * tanhf(v);
    }
    scores[i] = s + ba[0];
}

// ---------------------------------------------------------------- K3: per-tile softmax + stable-desc sort + cumsum + keep flags
__global__ __launch_bounds__(1024) void tile_kernel(const float* __restrict__ scores,
                                                    int* __restrict__ flags,
                                                    int* __restrict__ keepcnt) {
    const int t = blockIdx.x, tid = threadIdx.x;
    __shared__ float w[1024];
    __shared__ int   idx[1024];
    __shared__ float red[16];
    __shared__ int   keep_s;

    const int lane = tid & 63, wid = tid >> 6;
    float s = scores[t * 1024 + tid];

    // max reduce
    float m = s;
#pragma unroll
    for (int o = 32; o; o >>= 1) m = fmaxf(m, __shfl_xor(m, o));
    if (lane == 0) red[wid] = m;
    __syncthreads();
    float mb = red[0];
#pragma unroll
    for (int q = 1; q < 16; ++q) mb = fmaxf(mb, red[q]);
    __syncthreads();    // red reused below

    float e = expf(s - mb);
    float su = e;
#pragma unroll
    for (int o = 32; o; o >>= 1) su += __shfl_xor(su, o);
    if (lane == 0) red[wid] = su;
    __syncthreads();
    float tot = 0.f;
#pragma unroll
    for (int q = 0; q < 16; ++q) tot += red[q];

    float wv = e / tot;
    w[tid] = wv;
    idx[tid] = tid;
    __syncthreads();

    // bitonic sort, descending by (w desc, idx asc) — composite key reproduces
    // jnp's stable argsort(-w) exactly
    for (int kk = 2; kk <= 1024; kk <<= 1) {
        for (int j = kk >> 1; j > 0; j >>= 1) {
            int p = tid ^ j;
            if (p > tid) {
                float wa = w[tid], wb = w[p];
                int   ia = idx[tid], ib = idx[p];
                bool before = (wa > wb) || (wa == wb && ia < ib);
                bool desc = ((tid & kk) == 0);
                if (desc ? !before : before) {
                    w[tid] = wb; w[p] = wa;
                    idx[tid] = ib; idx[p] = ia;
                }
            }
            __syncthreads();
        }
    }

    // sequential cumsum (matches numpy accumulation order), keep = #(csum<0.9)+1
    if (tid == 0) {
        float c = 0.f; int kp = 0;
        for (int q = 0; q < 1024; ++q) { c += w[q]; if (c < 0.9f) ++kp; }
        keep_s = kp + 1;
        keepcnt[t] = kp + 1;
    }
    __syncthreads();

    // point idx[tid] (sorted position tid) kept iff tid < keep
    flags[t * 1024 + idx[tid]] = (tid < keep_s) ? 1 : 0;
}

// ---------------------------------------------------------------- K4: exclusive scan of per-tile keep counts (one wave, 8/lane)
__global__ __launch_bounds__(64) void offsets_kernel(const int* __restrict__ keepcnt,
                                                     int* __restrict__ toffs, int T) {
    const int lane = threadIdx.x;
    const int base = lane * 8;           // T = 512 = 64 lanes * 8
    int v[8]; int s = 0;
#pragma unroll
    for (int j = 0; j < 8; ++j) { v[j] = keepcnt[base + j]; s += v[j]; }
    int inc = s;
#pragma unroll
    for (int o = 1; o < 64; o <<= 1) {
        int tmp = __shfl_up(inc, o);
        if (lane >= o) inc += tmp;
    }
    int r = inc - s;                     // exclusive prefix
#pragma unroll
    for (int j = 0; j < 8; ++j) { toffs[base + j] = r; r += v[j]; }
}

// ---------------------------------------------------------------- K5: stream compaction (x rows + locations as float)
__global__ __launch_bounds__(1024) void compact_kernel(const float* __restrict__ x,
                                                       const int* __restrict__ locs,
                                                       const int* __restrict__ flags,
                                                       const int* __restrict__ toffs,
                                                       float* __restrict__ out,
                                                       int M) {
    const int t = blockIdx.x, tid = threadIdx.x;
    const long long gi = (long long)t * 1024 + tid;
    const int f = flags[gi];
    const int lane = tid & 63, wid = tid >> 6;

    unsigned long long ball = __ballot(f != 0);
    int wpre = __popcll(ball & (((unsigned long long)1 << lane) - 1ULL));

    __shared__ int wtot[16];
    __shared__ int woff[16];
    if (lane == 63) wtot[wid] = wpre + f;
    __syncthreads();
    if (tid == 0) {
        int r = 0;
#pragma unroll
        for (int q = 0; q < 16; ++q) { woff[q] = r; r += wtot[q]; }
    }
    __syncthreads();

    if (f) {
        const long long pos = (long long)toffs[t] + woff[wid] + wpre;
        const float4* src = (const float4*)(x + gi * 64);
        float4* dst = (float4*)(out + pos * 64);
#pragma unroll
        for (int j = 0; j < 16; ++j) dst[j] = src[j];
        float* lout = out + (long long)M * 64 + pos * 3;
        lout[0] = (float)locs[gi * 3 + 0];
        lout[1] = (float)locs[gi * 3 + 1];
        lout[2] = (float)locs[gi * 3 + 2];
    }
}

// ----------------------------------------------------------------
extern "C" void kernel_launch(void* const* d_in, const int* in_sizes, int n_in,
                              void* d_out, int out_size, void* d_ws, size_t ws_size,
                              hipStream_t stream) {
    const float* x    = (const float*)d_in[0];
    const int*   locs = (const int*)d_in[1];
    const float* y    = (const float*)d_in[2];
    const float* Wc   = (const float*)d_in[3];
    const float* bc   = (const float*)d_in[4];
    const float* Wy   = (const float*)d_in[5];
    const float* Wa   = (const float*)d_in[6];
    const float* ba   = (const float*)d_in[7];

    const int N = in_sizes[0] / 64;       // 524288
    const int T = N / 1024;               // 512
    const int M = out_size / 67;          // kept points (64 x-cols + 3 loc-cols)

    float* ws      = (float*)d_ws;
    float* yk      = ws;                      // 512 floats
    float* scores  = ws + 512;                // N floats
    int*   flags   = (int*)(ws + 512 + N);    // N ints
    int*   keepcnt = flags + N;               // T ints
    int*   toffs   = keepcnt + T;             // T ints

    yk_kernel<<<1, 512, 0, stream>>>(y, Wy, yk);
    score_kernel<<<N / 256, 256, 0, stream>>>(x, Wc, bc, Wa, ba, yk, scores);
    tile_kernel<<<T, 1024, 0, stream>>>(scores, flags, keepcnt);
    offsets_kernel<<<1, 64, 0, stream>>>(keepcnt, toffs, T);
    compact_kernel<<<T, 1024, 0, stream>>>(x, locs, flags, toffs, (float*)d_out, M);
}

// Round 3
// 225.292 us; speedup vs baseline: 1.2026x; 1.0503x over previous
//
#include <hip/hip_runtime.h>
#include <math.h>

// Problem constants: BS=8, FPS=64, PPF=1024, XC=64, K=64, YS=128
// N = 524288 points, T = 512 tiles (frames), batch = frame/64. CDF = 0.9

// ---------------------------------------------------------------- K1: y_k = y @ Wy.T  (8 x 64)
__global__ __launch_bounds__(512) void yk_kernel(const float* __restrict__ y,
                                                 const float* __restrict__ Wy,
                                                 float* __restrict__ yk) {
    const int tid = threadIdx.x;          // 512 = 8 batches * 64 k
    const int b = tid >> 6, k = tid & 63;
    const float* yrow = y + b * 128;
    const float* wrow = Wy + k * 128;
    float a0 = 0.f, a1 = 0.f, a2 = 0.f, a3 = 0.f;
#pragma unroll
    for (int j = 0; j < 128; j += 4) {
        a0 += yrow[j + 0] * wrow[j + 0];
        a1 += yrow[j + 1] * wrow[j + 1];
        a2 += yrow[j + 2] * wrow[j + 2];
        a3 += yrow[j + 3] * wrow[j + 3];
    }
    yk[tid] = (a0 + a1) + (a2 + a3);
}

// ---------------------------------------------------------------- K2: scores[i] = Wa . tanh(Wc x_i + bc + yk[b]) + ba
// Round-1/2 post-mortem: compiler allocated only 48 VGPRs and REMATERIALIZED
// the x row (re-loading it from L1/L2 inside the k-loop, legal since x is
// const __restrict__) -> kernel was L2-bound (~4.3 GB of x re-reads ~= 125us).
// Fix: pin the 64 loaded values as opaque asm outputs so they cannot be
// recomputed -> they must stay resident in VGPRs. Arithmetic order is
// bit-identical to the passing round-1 kernel.
__global__ __launch_bounds__(256, 4) void score_kernel(const float* __restrict__ x,
                                                       const float* __restrict__ Wc,
                                                       const float* __restrict__ bc,
                                                       const float* __restrict__ Wa,
                                                       const float* __restrict__ ba,
                                                       const float* __restrict__ yk,
                                                       float* __restrict__ scores) {
    __shared__ float sWc[64 * 64];
    __shared__ float sPre[64];   // bc[k] + yk[b][k]
    __shared__ float sWa[64];
    const int tid = threadIdx.x;
    const int b = blockIdx.x >> 8;                    // 256 blocks per batch
    const long long i = (long long)blockIdx.x * 256 + tid;

    for (int j = tid; j < 4096; j += 256) sWc[j] = Wc[j];
    if (tid < 64) {
        sPre[tid] = bc[tid] + yk[b * 64 + tid];
        sWa[tid]  = Wa[tid];
    }
    __syncthreads();

    // x row into registers (16 x float4), pinned opaque so the compiler
    // cannot rematerialize the loads inside the k-loop.
    float4 xq[16];
    const float4* xp = (const float4*)(x + i * 64);
#pragma unroll
    for (int j = 0; j < 16; ++j) xq[j] = xp[j];
#pragma unroll
    for (int j = 0; j < 16; ++j)
        asm volatile("" : "+v"(xq[j].x), "+v"(xq[j].y), "+v"(xq[j].z), "+v"(xq[j].w));

    float s = 0.f;
#pragma unroll 2
    for (int k = 0; k < 64; ++k) {
        const float* wr = &sWc[k * 64];            // wave-uniform LDS broadcast
        float a0 = 0.f, a1 = 0.f, a2 = 0.f, a3 = 0.f;
#pragma unroll
        for (int j = 0; j < 16; ++j) {
            a0 += xq[j].x * wr[4 * j + 0];
            a1 += xq[j].y * wr[4 * j + 1];
            a2 += xq[j].z * wr[4 * j + 2];
            a3 += xq[j].w * wr[4 * j + 3];
        }
        float v = ((a0 + a1) + (a2 + a3)) + sPre[k];
        s += sWa[k] * tanhf(v);
    }
    scores[i] = s + ba[0];
}

// ---------------------------------------------------------------- K3: per-tile softmax + stable-desc sort + cumsum + keep flags
__global__ __launch_bounds__(1024) void tile_kernel(const float* __restrict__ scores,
                                                    int* __restrict__ flags,
                                                    int* __restrict__ keepcnt) {
    const int t = blockIdx.x, tid = threadIdx.x;
    __shared__ float w[1024];
    __shared__ int   idx[1024];
    __shared__ float red[16];
    __shared__ int   keep_s;

    const int lane = tid & 63, wid = tid >> 6;
    float s = scores[t * 1024 + tid];

    // max reduce
    float m = s;
#pragma unroll
    for (int o = 32; o; o >>= 1) m = fmaxf(m, __shfl_xor(m, o));
    if (lane == 0) red[wid] = m;
    __syncthreads();
    float mb = red[0];
#pragma unroll
    for (int q = 1; q < 16; ++q) mb = fmaxf(mb, red[q]);
    __syncthreads();    // red reused below

    float e = expf(s - mb);
    float su = e;
#pragma unroll
    for (int o = 32; o; o >>= 1) su += __shfl_xor(su, o);
    if (lane == 0) red[wid] = su;
    __syncthreads();
    float tot = 0.f;
#pragma unroll
    for (int q = 0; q < 16; ++q) tot += red[q];

    float wv = e / tot;
    w[tid] = wv;
    idx[tid] = tid;
    __syncthreads();

    // bitonic sort, descending by (w desc, idx asc) — composite key reproduces
    // jnp's stable argsort(-w) exactly
    for (int kk = 2; kk <= 1024; kk <<= 1) {
        for (int j = kk >> 1; j > 0; j >>= 1) {
            int p = tid ^ j;
            if (p > tid) {
                float wa = w[tid], wb = w[p];
                int   ia = idx[tid], ib = idx[p];
                bool before = (wa > wb) || (wa == wb && ia < ib);
                bool desc = ((tid & kk) == 0);
                if (desc ? !before : before) {
                    w[tid] = wb; w[p] = wa;
                    idx[tid] = ib; idx[p] = ia;
                }
            }
            __syncthreads();
        }
    }

    // sequential cumsum (matches numpy accumulation order), keep = #(csum<0.9)+1
    if (tid == 0) {
        float c = 0.f; int kp = 0;
        for (int q = 0; q < 1024; ++q) { c += w[q]; if (c < 0.9f) ++kp; }
        keep_s = kp + 1;
        keepcnt[t] = kp + 1;
    }
    __syncthreads();

    // point idx[tid] (sorted position tid) kept iff tid < keep
    flags[t * 1024 + idx[tid]] = (tid < keep_s) ? 1 : 0;
}

// ---------------------------------------------------------------- K4: exclusive scan of per-tile keep counts (one wave, 8/lane)
__global__ __launch_bounds__(64) void offsets_kernel(const int* __restrict__ keepcnt,
                                                     int* __restrict__ toffs, int T) {
    const int lane = threadIdx.x;
    const int base = lane * 8;           // T = 512 = 64 lanes * 8
    int v[8]; int s = 0;
#pragma unroll
    for (int j = 0; j < 8; ++j) { v[j] = keepcnt[base + j]; s += v[j]; }
    int inc = s;
#pragma unroll
    for (int o = 1; o < 64; o <<= 1) {
        int tmp = __shfl_up(inc, o);
        if (lane >= o) inc += tmp;
    }
    int r = inc - s;                     // exclusive prefix
#pragma unroll
    for (int j = 0; j < 8; ++j) { toffs[base + j] = r; r += v[j]; }
}

// ---------------------------------------------------------------- K5: stream compaction (x rows + locations as float)
__global__ __launch_bounds__(1024) void compact_kernel(const float* __restrict__ x,
                                                       const int* __restrict__ locs,
                                                       const int* __restrict__ flags,
                                                       const int* __restrict__ toffs,
                                                       float* __restrict__ out,
                                                       int M) {
    const int t = blockIdx.x, tid = threadIdx.x;
    const long long gi = (long long)t * 1024 + tid;
    const int f = flags[gi];
    const int lane = tid & 63, wid = tid >> 6;

    unsigned long long ball = __ballot(f != 0);
    int wpre = __popcll(ball & (((unsigned long long)1 << lane) - 1ULL));

    __shared__ int wtot[16];
    __shared__ int woff[16];
    if (lane == 63) wtot[wid] = wpre + f;
    __syncthreads();
    if (tid == 0) {
        int r = 0;
#pragma unroll
        for (int q = 0; q < 16; ++q) { woff[q] = r; r += wtot[q]; }
    }
    __syncthreads();

    if (f) {
        const long long pos = (long long)toffs[t] + woff[wid] + wpre;
        const float4* src = (const float4*)(x + gi * 64);
        float4* dst = (float4*)(out + pos * 64);
#pragma unroll
        for (int j = 0; j < 16; ++j) dst[j] = src[j];
        float* lout = out + (long long)M * 64 + pos * 3;
        lout[0] = (float)locs[gi * 3 + 0];
        lout[1] = (float)locs[gi * 3 + 1];
        lout[2] = (float)locs[gi * 3 + 2];
    }
}

// ----------------------------------------------------------------
extern "C" void kernel_launch(void* const* d_in, const int* in_sizes, int n_in,
                              void* d_out, int out_size, void* d_ws, size_t ws_size,
                              hipStream_t stream) {
    const float* x    = (const float*)d_in[0];
    const int*   locs = (const int*)d_in[1];
    const float* y    = (const float*)d_in[2];
    const float* Wc   = (const float*)d_in[3];
    const float* bc   = (const float*)d_in[4];
    const float* Wy   = (const float*)d_in[5];
    const float* Wa   = (const float*)d_in[6];
    const float* ba   = (const float*)d_in[7];

    const int N = in_sizes[0] / 64;       // 524288
    const int T = N / 1024;               // 512
    const int M = out_size / 67;          // kept points (64 x-cols + 3 loc-cols)

    float* ws      = (float*)d_ws;
    float* yk      = ws;                      // 512 floats
    float* scores  = ws + 512;                // N floats
    int*   flags   = (int*)(ws + 512 + N);    // N ints
    int*   keepcnt = flags + N;               // T ints
    int*   toffs   = keepcnt + T;             // T ints

    yk_kernel<<<1, 512, 0, stream>>>(y, Wy, yk);
    score_kernel<<<N / 256, 256, 0, stream>>>(x, Wc, bc, Wa, ba, yk, scores);
    tile_kernel<<<T, 1024, 0, stream>>>(scores, flags, keepcnt);
    offsets_kernel<<<1, 64, 0, stream>>>(keepcnt, toffs, T);
    compact_kernel<<<T, 1024, 0, stream>>>(x, locs, flags, toffs, (float*)d_out, M);
}

// Round 4
// 196.975 us; speedup vs baseline: 1.3755x; 1.1438x over previous
//
#include <hip/hip_runtime.h>
#include <math.h>

// Problem constants: BS=8, FPS=64, PPF=1024, XC=64, K=64, YS=128
// N = 524288 points, T = 512 tiles (frames), batch = frame/64. CDF = 0.9

// ---------------------------------------------------------------- K1: y_k = y @ Wy.T  (8 x 64)
__global__ __launch_bounds__(512) void yk_kernel(const float* __restrict__ y,
                                                 const float* __restrict__ Wy,
                                                 float* __restrict__ yk) {
    const int tid = threadIdx.x;          // 512 = 8 batches * 64 k
    const int b = tid >> 6, k = tid & 63;
    const float* yrow = y + b * 128;
    const float* wrow = Wy + k * 128;
    float a0 = 0.f, a1 = 0.f, a2 = 0.f, a3 = 0.f;
#pragma unroll
    for (int j = 0; j < 128; j += 4) {
        a0 += yrow[j + 0] * wrow[j + 0];
        a1 += yrow[j + 1] * wrow[j + 1];
        a2 += yrow[j + 2] * wrow[j + 2];
        a3 += yrow[j + 3] * wrow[j + 3];
    }
    yk[tid] = (a0 + a1) + (a2 + a3);
}

// ---------------------------------------------------------------- K2: scores[i] = Wa . tanh(Wc x_i + bc + yk[b]) + ba
// Round-3 post-mortem: kernel was DS-pipe-bound — 1024 ds_read_b128 of the
// LDS Wc tile per wave (16/point) vs 64 FMA-instr/point; the per-CU DS pipe
// serialized ~33k reads/CU (~130-390k cyc) vs the 65k-cyc VALU floor.
// Fix: Wc/bc/Wa/yk are wave-UNIFORM -> read them straight from global with
// uniform addresses so the compiler uses the scalar path (s_load_dwordx16
// into SGPRs, K$-cached; v_fma takes one SGPR operand). No LDS, no barrier.
// x row stays pinned in 64 VGPRs (asm pin blocks rematerialization).
// Arithmetic order is identical to the passing kernel -> mask bit-identical.
__global__ __launch_bounds__(256, 4) void score_kernel(const float* __restrict__ x,
                                                       const float* __restrict__ Wc,
                                                       const float* __restrict__ bc,
                                                       const float* __restrict__ Wa,
                                                       const float* __restrict__ ba,
                                                       const float* __restrict__ yk,
                                                       float* __restrict__ scores) {
    const int tid = threadIdx.x;
    const int b = blockIdx.x >> 8;                    // 256 blocks per batch
    const long long i = (long long)blockIdx.x * 256 + tid;

    // x row into registers (16 x float4), pinned opaque so the compiler
    // cannot rematerialize the loads inside the k-loop.
    float4 xq[16];
    const float4* xp = (const float4*)(x + i * 64);
#pragma unroll
    for (int j = 0; j < 16; ++j) xq[j] = xp[j];
#pragma unroll
    for (int j = 0; j < 16; ++j)
        asm volatile("" : "+v"(xq[j].x), "+v"(xq[j].y), "+v"(xq[j].z), "+v"(xq[j].w));

    const float* __restrict__ ykb = yk + b * 64;      // uniform per block

    float s = 0.f;
    for (int k = 0; k < 64; ++k) {
        const float* __restrict__ wr = Wc + k * 64;   // wave-uniform -> s_load
        float a0 = 0.f, a1 = 0.f, a2 = 0.f, a3 = 0.f;
#pragma unroll
        for (int j = 0; j < 16; ++j) {
            a0 += xq[j].x * wr[4 * j + 0];
            a1 += xq[j].y * wr[4 * j + 1];
            a2 += xq[j].z * wr[4 * j + 2];
            a3 += xq[j].w * wr[4 * j + 3];
        }
        float v = ((a0 + a1) + (a2 + a3)) + (bc[k] + ykb[k]);
        s += Wa[k] * tanhf(v);
    }
    scores[i] = s + ba[0];
}

// ---------------------------------------------------------------- K3: per-tile softmax + stable-desc sort + cumsum + keep flags
__global__ __launch_bounds__(1024) void tile_kernel(const float* __restrict__ scores,
                                                    int* __restrict__ flags,
                                                    int* __restrict__ keepcnt) {
    const int t = blockIdx.x, tid = threadIdx.x;
    __shared__ float w[1024];
    __shared__ int   idx[1024];
    __shared__ float red[16];
    __shared__ int   keep_s;

    const int lane = tid & 63, wid = tid >> 6;
    float s = scores[t * 1024 + tid];

    // max reduce
    float m = s;
#pragma unroll
    for (int o = 32; o; o >>= 1) m = fmaxf(m, __shfl_xor(m, o));
    if (lane == 0) red[wid] = m;
    __syncthreads();
    float mb = red[0];
#pragma unroll
    for (int q = 1; q < 16; ++q) mb = fmaxf(mb, red[q]);
    __syncthreads();    // red reused below

    float e = expf(s - mb);
    float su = e;
#pragma unroll
    for (int o = 32; o; o >>= 1) su += __shfl_xor(su, o);
    if (lane == 0) red[wid] = su;
    __syncthreads();
    float tot = 0.f;
#pragma unroll
    for (int q = 0; q < 16; ++q) tot += red[q];

    float wv = e / tot;
    w[tid] = wv;
    idx[tid] = tid;
    __syncthreads();

    // bitonic sort, descending by (w desc, idx asc) — composite key reproduces
    // jnp's stable argsort(-w) exactly
    for (int kk = 2; kk <= 1024; kk <<= 1) {
        for (int j = kk >> 1; j > 0; j >>= 1) {
            int p = tid ^ j;
            if (p > tid) {
                float wa = w[tid], wb = w[p];
                int   ia = idx[tid], ib = idx[p];
                bool before = (wa > wb) || (wa == wb && ia < ib);
                bool desc = ((tid & kk) == 0);
                if (desc ? !before : before) {
                    w[tid] = wb; w[p] = wa;
                    idx[tid] = ib; idx[p] = ia;
                }
            }
            __syncthreads();
        }
    }

    // sequential cumsum (matches numpy accumulation order), keep = #(csum<0.9)+1
    if (tid == 0) {
        float c = 0.f; int kp = 0;
        for (int q = 0; q < 1024; ++q) { c += w[q]; if (c < 0.9f) ++kp; }
        keep_s = kp + 1;
        keepcnt[t] = kp + 1;
    }
    __syncthreads();

    // point idx[tid] (sorted position tid) kept iff tid < keep
    flags[t * 1024 + idx[tid]] = (tid < keep_s) ? 1 : 0;
}

// ---------------------------------------------------------------- K4: exclusive scan of per-tile keep counts (one wave, 8/lane)
__global__ __launch_bounds__(64) void offsets_kernel(const int* __restrict__ keepcnt,
                                                     int* __restrict__ toffs, int T) {
    const int lane = threadIdx.x;
    const int base = lane * 8;           // T = 512 = 64 lanes * 8
    int v[8]; int s = 0;
#pragma unroll
    for (int j = 0; j < 8; ++j) { v[j] = keepcnt[base + j]; s += v[j]; }
    int inc = s;
#pragma unroll
    for (int o = 1; o < 64; o <<= 1) {
        int tmp = __shfl_up(inc, o);
        if (lane >= o) inc += tmp;
    }
    int r = inc - s;                     // exclusive prefix
#pragma unroll
    for (int j = 0; j < 8; ++j) { toffs[base + j] = r; r += v[j]; }
}

// ---------------------------------------------------------------- K5: stream compaction (x rows + locations as float)
__global__ __launch_bounds__(1024) void compact_kernel(const float* __restrict__ x,
                                                       const int* __restrict__ locs,
                                                       const int* __restrict__ flags,
                                                       const int* __restrict__ toffs,
                                                       float* __restrict__ out,
                                                       int M) {
    const int t = blockIdx.x, tid = threadIdx.x;
    const long long gi = (long long)t * 1024 + tid;
    const int f = flags[gi];
    const int lane = tid & 63, wid = tid >> 6;

    unsigned long long ball = __ballot(f != 0);
    int wpre = __popcll(ball & (((unsigned long long)1 << lane) - 1ULL));

    __shared__ int wtot[16];
    __shared__ int woff[16];
    if (lane == 63) wtot[wid] = wpre + f;
    __syncthreads();
    if (tid == 0) {
        int r = 0;
#pragma unroll
        for (int q = 0; q < 16; ++q) { woff[q] = r; r += wtot[q]; }
    }
    __syncthreads();

    if (f) {
        const long long pos = (long long)toffs[t] + woff[wid] + wpre;
        const float4* src = (const float4*)(x + gi * 64);
        float4* dst = (float4*)(out + pos * 64);
#pragma unroll
        for (int j = 0; j < 16; ++j) dst[j] = src[j];
        float* lout = out + (long long)M * 64 + pos * 3;
        lout[0] = (float)locs[gi * 3 + 0];
        lout[1] = (float)locs[gi * 3 + 1];
        lout[2] = (float)locs[gi * 3 + 2];
    }
}

// ----------------------------------------------------------------
extern "C" void kernel_launch(void* const* d_in, const int* in_sizes, int n_in,
                              void* d_out, int out_size, void* d_ws, size_t ws_size,
                              hipStream_t stream) {
    const float* x    = (const float*)d_in[0];
    const int*   locs = (const int*)d_in[1];
    const float* y    = (const float*)d_in[2];
    const float* Wc   = (const float*)d_in[3];
    const float* bc   = (const float*)d_in[4];
    const float* Wy   = (const float*)d_in[5];
    const float* Wa   = (const float*)d_in[6];
    const float* ba   = (const float*)d_in[7];

    const int N = in_sizes[0] / 64;       // 524288
    const int T = N / 1024;               // 512
    const int M = out_size / 67;          // kept points (64 x-cols + 3 loc-cols)

    float* ws      = (float*)d_ws;
    float* yk      = ws;                      // 512 floats
    float* scores  = ws + 512;                // N floats
    int*   flags   = (int*)(ws + 512 + N);    // N ints
    int*   keepcnt = flags + N;               // T ints
    int*   toffs   = keepcnt + T;             // T ints

    yk_kernel<<<1, 512, 0, stream>>>(y, Wy, yk);
    score_kernel<<<N / 256, 256, 0, stream>>>(x, Wc, bc, Wa, ba, yk, scores);
    tile_kernel<<<T, 1024, 0, stream>>>(scores, flags, keepcnt);
    offsets_kernel<<<1, 64, 0, stream>>>(keepcnt, toffs, T);
    compact_kernel<<<T, 1024, 0, stream>>>(x, locs, flags, toffs, (float*)d_out, M);
}